// Round 7
// baseline (172.240 us; speedup 1.0000x reference)
//
#include <hip/hip_runtime.h>

#define NB 512
#define NT 512
#define NL 64
#define L2E 1.4426950408889634f   // log2(e)
#define LN2 0.6931471805599453f   // ln(2)

typedef _Float16 h2 __attribute__((ext_vector_type(2)));

__global__ void zero_out_kernel(float* out) { *out = 0.0f; }

// R16: chain-hop surgery on the R15b engine. Model (fits R10-R15): step =
// ~600cy fixed + 2.7cy/instr; VALUBusy back-computation => actual clock
// ~1 GHz and ~15cy per dependent hop * ~18 hops = the fixed term. So cut
// hops, not just instrs:
//  1. EARLY RESCALE: DOTQ(0) computed first; RFL exponent taken from lane0's
//     16-term partial F0 -> readfirstlane/SALU/scale overlap the remaining
//     dots + permlane reduce (was serial after them). Renormalize to
//     exponent -6: E in [0.905,1.105] keeps the partial within a few bits
//     of any output; 2^14 f16 overflow headroom vs estimate error; still
//     above harmful subnormals. Exact 2^k scales => bit-identical rounding
//     trajectory, G bookkeeping exact.
//  2. fs = eemu_sel * scale fused OFF-chain (both ready mid-reduce);
//     chain tail = mul fs -> cndmask (2 hops, was ~5).
//  3. dot add-tree: 8 chains depth-2 + 2-level tree (depth 4, was 5).
// Everything else (packed-DPP gather w/ probed permutation, permlane
// self-swap reduce, raw prefetch ring, mask ballots, path score, fwd/bwd
// T/2 split, junction) verbatim from R15b.

template <int K>
__device__ __forceinline__ unsigned roru(unsigned x) {
  if constexpr (K == 0) return x;
  else
    return (unsigned)__builtin_amdgcn_mov_dpp((int)x, 0x120 + K, 0xF, 0xF, true);
}

__device__ __forceinline__ float dot2f(h2 a, h2 b, float c) {
#if __has_builtin(__builtin_amdgcn_fdot2)
  return __builtin_amdgcn_fdot2(a, b, c, false);
#else
  return fmaf((float)a[0], (float)b[0], fmaf((float)a[1], (float)b[1], c));
#endif
}

__device__ __forceinline__ h2 pkrtz(float a, float b) {
#if __has_builtin(__builtin_amdgcn_cvt_pkrtz)
  return __builtin_bit_cast(h2, __builtin_amdgcn_cvt_pkrtz(a, b));
#else
  h2 v; v[0] = (_Float16)a; v[1] = (_Float16)b; return v;
#endif
}

__device__ __forceinline__ float pairsum16(float x) {
#if __has_builtin(__builtin_amdgcn_permlane16_swap)
  unsigned xu = __float_as_uint(x);
  auto rp = __builtin_amdgcn_permlane16_swap(xu, xu, false, false);
  return __uint_as_float(rp[0]) + __uint_as_float(rp[1]);
#else
  return x + __shfl_xor(x, 16, 64);
#endif
}
__device__ __forceinline__ float pairsum32(float x) {
#if __has_builtin(__builtin_amdgcn_permlane32_swap)
  unsigned xu = __float_as_uint(x);
  auto rp = __builtin_amdgcn_permlane32_swap(xu, xu, false, false);
  return __uint_as_float(rp[0]) + __uint_as_float(rp[1]);
#else
  return x + __shfl_xor(x, 32, 64);
#endif
}

__device__ __forceinline__ h2 bch2(unsigned u) { return __builtin_bit_cast(h2, u); }

// 64x64 matvec with early-exponent rescale. Returns the (unscaled) output
// for this lane; scale = 2^(121-e0) (renormalizes lane0's q=0 partial to
// exponent -6) is produced EARLY so the caller's fs-mul is off-chain.
__device__ __forceinline__ float matvec_core(float sval, const h2 (&ep)[4][8],
                                             int r, float& scale, int& G) {
  float s1 = __uint_as_float(roru<1>(__float_as_uint(sval)));
  unsigned u0 = __builtin_bit_cast(unsigned, pkrtz(sval, s1));
  unsigned u1 = roru<2>(u0);
  unsigned u2 = roru<4>(u0);
  unsigned u3 = roru<6>(u0);
  unsigned u4 = roru<8>(u0);
  unsigned u5 = roru<10>(u0);
  unsigned u6 = roru<12>(u0);
  unsigned u7 = roru<14>(u0);
  float F0, F1, F2, F3;
#define DOTQ(Q, DST)                                   \
  {                                                    \
    float a1 = dot2f(bch2(u0), ep[Q][0], 0.0f);        \
    a1 = dot2f(bch2(u1), ep[Q][1], a1);                \
    float a2 = dot2f(bch2(u2), ep[Q][2], 0.0f);        \
    a2 = dot2f(bch2(u3), ep[Q][3], a2);                \
    float b1 = dot2f(bch2(u4), ep[Q][4], 0.0f);        \
    b1 = dot2f(bch2(u5), ep[Q][5], b1);                \
    float b2 = dot2f(bch2(u6), ep[Q][6], 0.0f);        \
    b2 = dot2f(bch2(u7), ep[Q][7], b2);                \
    DST = (a1 + a2) + (b1 + b2);                       \
  }
  DOTQ(0, F0)
  // early exponent estimate from lane0's 16-term positive partial;
  // RFL/SALU overlap DOTQ(1..3) + the permlane reduce below.
  unsigned e0 =
      (__builtin_amdgcn_readfirstlane(__float_as_uint(F0)) >> 23) & 0xffu;
  scale = __uint_as_float((248u - e0) << 23);   // 2^(121-e0), exact
  G += (int)e0 - 121;
  DOTQ(1, F1) DOTQ(2, F2) DOTQ(3, F3)
#undef DOTQ
  F0 = pairsum32(pairsum16(F0));
  F1 = pairsum32(pairsum16(F1));
  F2 = pairsum32(pairsum16(F2));
  F3 = pairsum32(pairsum16(F3));
  float ya = (r & 1) ? F1 : F0;
  float yb = (r & 1) ? F3 : F2;
  return (r & 2) ? yb : ya;
}

__global__
__attribute__((amdgpu_flat_work_group_size(128, 128), amdgpu_waves_per_eu(1, 1)))
void crf_nll_kernel(
    const float* __restrict__ emission,     // B,T,L
    const int*   __restrict__ target,       // B,T
    const float* __restrict__ mask,         // B,T
    const float* __restrict__ start_trans,  // L
    const float* __restrict__ trans,        // L,L
    const float* __restrict__ end_trans,    // L
    float* __restrict__ out)
{
  const int b = blockIdx.x;
  const int tid = threadIdx.x;
  const int wv = tid >> 6;            // 0 = forward, 1 = backward
  const int j = tid & 63;
  const int r = j >> 4;
  const int c = j & 15;

  const float* em_b = emission + (size_t)b * NT * NL;
  const float* mk_b = mask + (size_t)b * NT;
  const int*   tg_b = target + (size_t)b * NT;

  __shared__ float fF[NL], fB[NL];
  __shared__ float psS[2];
  __shared__ int   GS[2];

  // ---- probe the gather permutation. Pair m of the packed-DPP net holds
  // ---- (s[e0x[m]], s[e1x[m]]) with e0x[m] = sig2m(c), e1x[m] = sig1(sig2m(c)).
  int e0x[8], e1x[8];
  {
    unsigned cu = (unsigned)c;
    unsigned c1 = roru<1>(cu);
    e0x[0] = (int)cu;  e1x[0] = (int)c1;
#define PRB(M) e0x[M] = (int)roru<2 * M>(cu); e1x[M] = (int)roru<2 * M>(c1);
    PRB(1) PRB(2) PRB(3) PRB(4) PRB(5) PRB(6) PRB(7)
#undef PRB
  }

  // ------- path score: wave wv covers chunks [4wv, 4wv+4) = its T half -----
  float ps = 0.0f;
  #pragma unroll
  for (int cc = 4 * wv; cc < 4 * wv + 4; ++cc) {
    int t = cc * 64 + j;
    int cur = tg_b[t];
    float m  = mk_b[t];
    float mn = (t + 1 < NT) ? mk_b[t + 1] : 0.0f;
    if (t == 0) {
      ps += start_trans[cur] + em_b[cur];
    } else {
      int prev = tg_b[t - 1];
      if (m > 0.5f)
        ps += trans[prev * NL + cur] + em_b[(size_t)t * NL + cur];
      if (m - mn > 0.5f)                 // end_mask = m_t & !m_{t+1}
        ps += end_trans[cur];
    }
  }
  #pragma unroll
  for (int off = 32; off; off >>= 1) ps += __shfl_down(ps, off, 64);

  const float endt = __builtin_amdgcn_exp2f(L2E * end_trans[j]);

  int G = 0;          // exact integer scale deficit (log2 units): true = s*2^G
  float s;

  if (wv == 0) {
    // ======================= FORWARD: t = 0..255 ===========================
    // y = E^T s: ep[q][m] = h2(exp(trans[16r+e0x[m]][16q+c]),
    //                          exp(trans[16r+e1x[m]][16q+c]))
    h2 ep[4][8];
    #pragma unroll
    for (int q = 0; q < 4; ++q) {
      const int col = 16 * q + c;
      #pragma unroll
      for (int m = 0; m < 8; ++m) {
        float e0 = __builtin_amdgcn_exp2f(L2E * trans[(16 * r + e0x[m]) * NL + col]);
        float e1 = __builtin_amdgcn_exp2f(L2E * trans[(16 * r + e1x[m]) * NL + col]);
        h2 v; v[0] = (_Float16)e0; v[1] = (_Float16)e1;
        ep[q][m] = v;
      }
    }
    s = __builtin_amdgcn_exp2f(L2E * (start_trans[j] + em_b[j]));  // t=0

    // raw prefetch ring: pfr[u] = em[t][j] for upcoming step t (t&7 == u)
    float pfr[8];
    #pragma unroll
    for (int u = 0; u < 8; ++u) pfr[u] = em_b[(size_t)u * NL + j];

    float mlv = mk_b[j];
    float mnv = mk_b[j + 1];

    #pragma unroll 1
    for (int cc = 0; cc < 4; ++cc) {
      const int tb = cc * 64;
      unsigned long long cm = __ballot(mlv > 0.5f);
      unsigned long long ce = __ballot(mlv - mnv > 0.5f);
      if (cc == 0) { cm &= ~1ull; ce &= ~1ull; }  // t=0 handled by init
      mlv = mk_b[tb + 64 + j];          // next block (max 320 < NT)
      mnv = mk_b[tb + 64 + j + 1];

      #pragma unroll 1
      for (int i8 = 0; i8 < 64; i8 += 8) {
        #pragma unroll
        for (int u = 0; u < 8; ++u) {
          const int i = i8 + u;
          const int t = tb + i;
          float pv = pfr[u];
          pfr[u] = em_b[(size_t)(t + 8) * NL + j];   // t+8 <= 263 < NT
          float eemu = __builtin_amdgcn_exp2f(L2E * pv);
          eemu = ((ce >> i) & 1) ? eemu * endt : eemu;
          // chain: matvec -> mul fs -> cndmask (scale/fs arrive off-chain)
          float scale;
          float sm = matvec_core(s, ep, r, scale, G);
          float fs = eemu * scale;                   // off-chain fuse
          float snew = sm * fs;
          float sold = s * scale;
          s = ((cm >> i) & 1) ? snew : sold;
        }
      }
    }
  } else {
    // ======================= BACKWARD: t = 511..256 ========================
    // v' = E (v o w): ep[q][m] = h2(exp(trans[16q+c][16r+e0x[m]]),
    //                               exp(trans[16q+c][16r+e1x[m]]))
    h2 ep[4][8];
    #pragma unroll
    for (int q = 0; q < 4; ++q) {
      const int rowi = 16 * q + c;
      #pragma unroll
      for (int m = 0; m < 8; ++m) {
        float e0 = __builtin_amdgcn_exp2f(L2E * trans[rowi * NL + 16 * r + e0x[m]]);
        float e1 = __builtin_amdgcn_exp2f(L2E * trans[rowi * NL + 16 * r + e1x[m]]);
        h2 v; v[0] = (_Float16)e0; v[1] = (_Float16)e1;
        ep[q][m] = v;
      }
    }
    s = 1.0f;                                   // v^T = 1^T

    float pfr[8];                                // slot t&7; boots 511..504
    #pragma unroll
    for (int u = 0; u < 8; ++u) pfr[u] = em_b[(size_t)(504 + u) * NL + j];

    float mlv = mk_b[448 + j];
    int nidx0 = 448 + j + 1;
    float mnv = (nidx0 < NT) ? mk_b[nidx0] : 0.0f;

    #pragma unroll 1
    for (int cc = 7; cc >= 4; --cc) {
      const int tb = cc * 64;
      unsigned long long cm = __ballot(mlv > 0.5f);
      unsigned long long ce = __ballot(mlv - mnv > 0.5f);
      mlv = mk_b[tb - 64 + j];          // prev block (min 192, max 256 < NT)
      mnv = mk_b[tb - 64 + j + 1];

      #pragma unroll 1
      for (int i8 = 56; i8 >= 0; i8 -= 8) {
        #pragma unroll
        for (int u = 7; u >= 0; --u) {
          const int i = i8 + u;
          const int t = tb + i;                  // t & 7 == u
          float pv = pfr[u];
          pfr[u] = em_b[(size_t)(t - 8) * NL + j];   // t-8 >= 248
          float eemu = __builtin_amdgcn_exp2f(L2E * pv);
          float wmul = ((cm >> i) & 1) ? eemu : 1.0f;
          wmul = ((ce >> i) & 1) ? wmul * endt : wmul;
          float w = s * wmul;
          if ((cm >> i) & 1) {
            float scale;
            float sm = matvec_core(w, ep, r, scale, G);
            s = sm * scale;
          } else {
            s = w;                               // A_t = I (masked-out step)
          }
        }
      }
    }
  }

  // ---------------- junction: norm = log(v . q) + (Gf+Gb)*ln2 ---------------
  if (wv == 0) { fF[j] = s; if (j == 0) { psS[0] = ps; GS[0] = G; } }
  else         { fB[j] = s; if (j == 0) { psS[1] = ps; GS[1] = G; } }
  __syncthreads();
  if (wv == 0) {
    float prod = s * fB[j];
    #pragma unroll
    for (int off = 32; off; off >>= 1) prod += __shfl_xor(prod, off, 64);
    if (j == 0) {
      float norm = (__builtin_amdgcn_logf(prod) + (float)(GS[0] + GS[1])) * LN2;
      atomicAdd(out, (norm - psS[0] - psS[1]) * (1.0f / (float)NB));
    }
  }
}

extern "C" void kernel_launch(void* const* d_in, const int* in_sizes, int n_in,
                              void* d_out, int out_size, void* d_ws, size_t ws_size,
                              hipStream_t stream) {
  const float* emission    = (const float*)d_in[0];
  const int*   target      = (const int*)  d_in[1];
  const float* mask        = (const float*)d_in[2];
  const float* start_trans = (const float*)d_in[3];
  const float* trans       = (const float*)d_in[4];
  const float* end_trans   = (const float*)d_in[5];
  float* out = (float*)d_out;

  zero_out_kernel<<<1, 1, 0, stream>>>(out);
  crf_nll_kernel<<<NB, 128, 0, stream>>>(emission, target, mask, start_trans,
                                         trans, end_trans, out);
}

// Round 8
// 167.712 us; speedup vs baseline: 1.0270x; 1.0270x over previous
//
#include <hip/hip_runtime.h>

#define NB 512
#define NT 512
#define NL 64
#define L2E 1.4426950408889634f   // log2(e)
#define LN2 0.6931471805599453f   // ln(2)

typedef _Float16 h2 __attribute__((ext_vector_type(2)));

__global__ void zero_out_kernel(float* out) { *out = 0.0f; }

// R17: delayed-exponent rescale on the R15b engine. R16 post-mortem: early
// RFL between dot groups regressed (convergent op mid-computation blocks
// scheduler interleaving). Model: step = ~640cy fixed (19 dep hops) +
// 2.2cy/instr. Fix: the rescale scale needs to be SOME exact 2^k, not THE
// current exponent -- so derive it from the PREVIOUS step's sm (RFL runs at
// step end, overlapping the next step's gather+dots; ~11 hops of slack).
// Tail shrinks to msel=cndmask(sm,s) -> mul fsel (2 hops, fsel off-chain).
// Renorm target 2^-4 centers f16-pack headroom vs the 1-step exponent
// drift (<=2^8 on N(0,1) data). G += kcur matches the scale actually
// applied each step -- bookkeeping stays exact. DOTQ reverted to R15b's
// measured-faster 2-chain depth-4 form. Everything else (packed-DPP gather
// w/ probed permutation, permlane self-swap reduce, raw prefetch ring,
// mask ballots, path score, fwd/bwd T/2 split, junction) verbatim R15b.

template <int K>
__device__ __forceinline__ unsigned roru(unsigned x) {
  if constexpr (K == 0) return x;
  else
    return (unsigned)__builtin_amdgcn_mov_dpp((int)x, 0x120 + K, 0xF, 0xF, true);
}

__device__ __forceinline__ float dot2f(h2 a, h2 b, float c) {
#if __has_builtin(__builtin_amdgcn_fdot2)
  return __builtin_amdgcn_fdot2(a, b, c, false);
#else
  return fmaf((float)a[0], (float)b[0], fmaf((float)a[1], (float)b[1], c));
#endif
}

__device__ __forceinline__ h2 pkrtz(float a, float b) {
#if __has_builtin(__builtin_amdgcn_cvt_pkrtz)
  return __builtin_bit_cast(h2, __builtin_amdgcn_cvt_pkrtz(a, b));
#else
  h2 v; v[0] = (_Float16)a; v[1] = (_Float16)b; return v;
#endif
}

__device__ __forceinline__ float pairsum16(float x) {
#if __has_builtin(__builtin_amdgcn_permlane16_swap)
  unsigned xu = __float_as_uint(x);
  auto rp = __builtin_amdgcn_permlane16_swap(xu, xu, false, false);
  return __uint_as_float(rp[0]) + __uint_as_float(rp[1]);
#else
  return x + __shfl_xor(x, 16, 64);
#endif
}
__device__ __forceinline__ float pairsum32(float x) {
#if __has_builtin(__builtin_amdgcn_permlane32_swap)
  unsigned xu = __float_as_uint(x);
  auto rp = __builtin_amdgcn_permlane32_swap(xu, xu, false, false);
  return __uint_as_float(rp[0]) + __uint_as_float(rp[1]);
#else
  return x + __shfl_xor(x, 32, 64);
#endif
}

__device__ __forceinline__ h2 bch2(unsigned u) { return __builtin_bit_cast(h2, u); }

// 64x64 matvec: gather packed pairs via DPP, 32 dot2 (8 chains depth 4),
// permlane transpose-reduce, select q == r. Pure: no rescale inside.
__device__ __forceinline__ float matvec64d(float sval, const h2 (&ep)[4][8],
                                           int r) {
  float s1 = __uint_as_float(roru<1>(__float_as_uint(sval)));
  unsigned u0 = __builtin_bit_cast(unsigned, pkrtz(sval, s1));
  unsigned u1 = roru<2>(u0);
  unsigned u2 = roru<4>(u0);
  unsigned u3 = roru<6>(u0);
  unsigned u4 = roru<8>(u0);
  unsigned u5 = roru<10>(u0);
  unsigned u6 = roru<12>(u0);
  unsigned u7 = roru<14>(u0);
  float F0, F1, F2, F3;
#define DOTQ(Q, DST)                              \
  {                                               \
    float a = dot2f(bch2(u0), ep[Q][0], 0.0f);    \
    a = dot2f(bch2(u1), ep[Q][1], a);             \
    a = dot2f(bch2(u2), ep[Q][2], a);             \
    a = dot2f(bch2(u3), ep[Q][3], a);             \
    float b = dot2f(bch2(u4), ep[Q][4], 0.0f);    \
    b = dot2f(bch2(u5), ep[Q][5], b);             \
    b = dot2f(bch2(u6), ep[Q][6], b);             \
    b = dot2f(bch2(u7), ep[Q][7], b);             \
    DST = a + b;                                  \
  }
  DOTQ(0, F0) DOTQ(1, F1) DOTQ(2, F2) DOTQ(3, F3)
#undef DOTQ
  F0 = pairsum32(pairsum16(F0));
  F1 = pairsum32(pairsum16(F1));
  F2 = pairsum32(pairsum16(F2));
  F3 = pairsum32(pairsum16(F3));
  float ya = (r & 1) ? F1 : F0;
  float yb = (r & 1) ? F3 : F2;
  return (r & 2) ? yb : ya;
}

__global__
__attribute__((amdgpu_flat_work_group_size(128, 128), amdgpu_waves_per_eu(1, 1)))
void crf_nll_kernel(
    const float* __restrict__ emission,     // B,T,L
    const int*   __restrict__ target,       // B,T
    const float* __restrict__ mask,         // B,T
    const float* __restrict__ start_trans,  // L
    const float* __restrict__ trans,        // L,L
    const float* __restrict__ end_trans,    // L
    float* __restrict__ out)
{
  const int b = blockIdx.x;
  const int tid = threadIdx.x;
  const int wv = tid >> 6;            // 0 = forward, 1 = backward
  const int j = tid & 63;
  const int r = j >> 4;
  const int c = j & 15;

  const float* em_b = emission + (size_t)b * NT * NL;
  const float* mk_b = mask + (size_t)b * NT;
  const int*   tg_b = target + (size_t)b * NT;

  __shared__ float fF[NL], fB[NL];
  __shared__ float psS[2];
  __shared__ int   GS[2];

  // ---- probe the gather permutation. Pair m of the packed-DPP net holds
  // ---- (s[e0x[m]], s[e1x[m]]) with e0x[m] = sig2m(c), e1x[m] = sig1(sig2m(c)).
  int e0x[8], e1x[8];
  {
    unsigned cu = (unsigned)c;
    unsigned c1 = roru<1>(cu);
    e0x[0] = (int)cu;  e1x[0] = (int)c1;
#define PRB(M) e0x[M] = (int)roru<2 * M>(cu); e1x[M] = (int)roru<2 * M>(c1);
    PRB(1) PRB(2) PRB(3) PRB(4) PRB(5) PRB(6) PRB(7)
#undef PRB
  }

  // ------- path score: wave wv covers chunks [4wv, 4wv+4) = its T half -----
  float ps = 0.0f;
  #pragma unroll
  for (int cc = 4 * wv; cc < 4 * wv + 4; ++cc) {
    int t = cc * 64 + j;
    int cur = tg_b[t];
    float m  = mk_b[t];
    float mn = (t + 1 < NT) ? mk_b[t + 1] : 0.0f;
    if (t == 0) {
      ps += start_trans[cur] + em_b[cur];
    } else {
      int prev = tg_b[t - 1];
      if (m > 0.5f)
        ps += trans[prev * NL + cur] + em_b[(size_t)t * NL + cur];
      if (m - mn > 0.5f)                 // end_mask = m_t & !m_{t+1}
        ps += end_trans[cur];
    }
  }
  #pragma unroll
  for (int off = 32; off; off >>= 1) ps += __shfl_down(ps, off, 64);

  const float endt = __builtin_amdgcn_exp2f(L2E * end_trans[j]);

  int G = 0;          // exact integer scale deficit (log2 units): true = s*2^G
  float s;

  if (wv == 0) {
    // ======================= FORWARD: t = 0..255 ===========================
    // y = E^T s: ep[q][m] = h2(exp(trans[16r+e0x[m]][16q+c]),
    //                          exp(trans[16r+e1x[m]][16q+c]))
    h2 ep[4][8];
    #pragma unroll
    for (int q = 0; q < 4; ++q) {
      const int col = 16 * q + c;
      #pragma unroll
      for (int m = 0; m < 8; ++m) {
        float e0 = __builtin_amdgcn_exp2f(L2E * trans[(16 * r + e0x[m]) * NL + col]);
        float e1 = __builtin_amdgcn_exp2f(L2E * trans[(16 * r + e1x[m]) * NL + col]);
        h2 v; v[0] = (_Float16)e0; v[1] = (_Float16)e1;
        ep[q][m] = v;
      }
    }
    s = __builtin_amdgcn_exp2f(L2E * (start_trans[j] + em_b[j]));  // t=0

    // delayed-scale state: scale_cur = exact 2^(-kcur), applied EVERY step;
    // init estimate from s_init's exponent +6 (the 64-sum bias of sm).
    int kcur; float scale_cur;
    {
      unsigned e =
          (__builtin_amdgcn_readfirstlane(__float_as_uint(s)) >> 23) & 0xffu;
      kcur = (int)e - 117;                         // target 2^-4, +6 sum bias
      scale_cur = __uint_as_float((244u - e) << 23);
    }

    // raw prefetch ring: pfr[u] = em[t][j] for upcoming step t (t&7 == u)
    float pfr[8];
    #pragma unroll
    for (int u = 0; u < 8; ++u) pfr[u] = em_b[(size_t)u * NL + j];

    float mlv = mk_b[j];
    float mnv = mk_b[j + 1];

    #pragma unroll 1
    for (int cc = 0; cc < 4; ++cc) {
      const int tb = cc * 64;
      unsigned long long cm = __ballot(mlv > 0.5f);
      unsigned long long ce = __ballot(mlv - mnv > 0.5f);
      if (cc == 0) { cm &= ~1ull; ce &= ~1ull; }  // t=0 handled by init
      mlv = mk_b[tb + 64 + j];          // next block (max 320 < NT)
      mnv = mk_b[tb + 64 + j + 1];

      #pragma unroll 1
      for (int i8 = 0; i8 < 64; i8 += 8) {
        #pragma unroll
        for (int u = 0; u < 8; ++u) {
          const int i = i8 + u;
          const int t = tb + i;
          float pv = pfr[u];
          pfr[u] = em_b[(size_t)(t + 8) * NL + j];   // t+8 <= 263 < NT
          // off-chain: eemu, fs, fsel (scale_cur/kcur from PREVIOUS step)
          float eemu = __builtin_amdgcn_exp2f(L2E * pv);
          eemu = ((ce >> i) & 1) ? eemu * endt : eemu;
          const bool bit = (cm >> i) & 1;
          float fs = eemu * scale_cur;
          float fsel = bit ? fs : scale_cur;
          // chain: matvec -> msel -> mul (2-hop tail)
          float sm = matvec64d(s, ep, r);
          float msel = bit ? sm : s;
          s = msel * fsel;
          G += kcur;                                 // matches applied scale
          // end-of-step: next scale from THIS sm (overlaps next gather+dots)
          unsigned e =
            (__builtin_amdgcn_readfirstlane(__float_as_uint(sm)) >> 23) & 0xffu;
          kcur = bit ? (int)e - 123 : kcur;          // target 2^-4
          scale_cur = bit ? __uint_as_float((250u - e) << 23) : scale_cur;
        }
      }
    }
  } else {
    // ======================= BACKWARD: t = 511..256 ========================
    // v' = E (v o w): ep[q][m] = h2(exp(trans[16q+c][16r+e0x[m]]),
    //                               exp(trans[16q+c][16r+e1x[m]]))
    h2 ep[4][8];
    #pragma unroll
    for (int q = 0; q < 4; ++q) {
      const int rowi = 16 * q + c;
      #pragma unroll
      for (int m = 0; m < 8; ++m) {
        float e0 = __builtin_amdgcn_exp2f(L2E * trans[rowi * NL + 16 * r + e0x[m]]);
        float e1 = __builtin_amdgcn_exp2f(L2E * trans[rowi * NL + 16 * r + e1x[m]]);
        h2 v; v[0] = (_Float16)e0; v[1] = (_Float16)e1;
        ep[q][m] = v;
      }
    }
    s = 1.0f;                                   // v^T = 1^T
    // delayed-scale init from s=1 (e=127) + 6-sum bias: target 2^-4
    int kcur = 127 - 117;
    float scale_cur = __uint_as_float((244u - 127u) << 23);

    float pfr[8];                                // slot t&7; boots 511..504
    #pragma unroll
    for (int u = 0; u < 8; ++u) pfr[u] = em_b[(size_t)(504 + u) * NL + j];

    float mlv = mk_b[448 + j];
    int nidx0 = 448 + j + 1;
    float mnv = (nidx0 < NT) ? mk_b[nidx0] : 0.0f;

    #pragma unroll 1
    for (int cc = 7; cc >= 4; --cc) {
      const int tb = cc * 64;
      unsigned long long cm = __ballot(mlv > 0.5f);
      unsigned long long ce = __ballot(mlv - mnv > 0.5f);
      mlv = mk_b[tb - 64 + j];          // prev block (min 192, max 256 < NT)
      mnv = mk_b[tb - 64 + j + 1];

      #pragma unroll 1
      for (int i8 = 56; i8 >= 0; i8 -= 8) {
        #pragma unroll
        for (int u = 7; u >= 0; --u) {
          const int i = i8 + u;
          const int t = tb + i;                  // t & 7 == u
          float pv = pfr[u];
          pfr[u] = em_b[(size_t)(t - 8) * NL + j];   // t-8 >= 248
          float eemu = __builtin_amdgcn_exp2f(L2E * pv);
          const bool bit = (cm >> i) & 1;
          float wmul = bit ? eemu : 1.0f;
          wmul = ((ce >> i) & 1) ? wmul * endt : wmul;
          float w = s * wmul;
          if (bit) {
            float sm = matvec64d(w, ep, r);
            s = sm * scale_cur;                      // off-chain scale
            G += kcur;
            unsigned e =
              (__builtin_amdgcn_readfirstlane(__float_as_uint(sm)) >> 23) & 0xffu;
            kcur = (int)e - 123;                     // target 2^-4
            scale_cur = __uint_as_float((250u - e) << 23);
          } else {
            s = w;                               // A_t = I (masked-out step)
          }
        }
      }
    }
  }

  // ---------------- junction: norm = log(v . q) + (Gf+Gb)*ln2 ---------------
  if (wv == 0) { fF[j] = s; if (j == 0) { psS[0] = ps; GS[0] = G; } }
  else         { fB[j] = s; if (j == 0) { psS[1] = ps; GS[1] = G; } }
  __syncthreads();
  if (wv == 0) {
    float prod = s * fB[j];
    #pragma unroll
    for (int off = 32; off; off >>= 1) prod += __shfl_xor(prod, off, 64);
    if (j == 0) {
      float norm = (__builtin_amdgcn_logf(prod) + (float)(GS[0] + GS[1])) * LN2;
      atomicAdd(out, (norm - psS[0] - psS[1]) * (1.0f / (float)NB));
    }
  }
}

extern "C" void kernel_launch(void* const* d_in, const int* in_sizes, int n_in,
                              void* d_out, int out_size, void* d_ws, size_t ws_size,
                              hipStream_t stream) {
  const float* emission    = (const float*)d_in[0];
  const int*   target      = (const int*)  d_in[1];
  const float* mask        = (const float*)d_in[2];
  const float* start_trans = (const float*)d_in[3];
  const float* trans       = (const float*)d_in[4];
  const float* end_trans   = (const float*)d_in[5];
  float* out = (float*)d_out;

  zero_out_kernel<<<1, 1, 0, stream>>>(out);
  crf_nll_kernel<<<NB, 128, 0, stream>>>(emission, target, mask, start_trans,
                                         trans, end_trans, out);
}